// Round 6
// baseline (1198.211 us; speedup 1.0000x reference)
//
#include <hip/hip_runtime.h>
#include <cstddef>

#define N_NODES 20000
#define N_EDGES 320000
#define IN_CH   64
#define HID     512
#define G4      2048
#define BN_EPS  1e-5f

typedef __attribute__((ext_vector_type(8))) __bf16 bf16x8;
typedef __attribute__((ext_vector_type(4))) float f32x4;

__device__ __forceinline__ float sigmoidf_(float x) {
  return 1.0f / (1.0f + expf(-x));
}

// fp32 -> bf16 (RNE)
__device__ __forceinline__ unsigned short f2b(float f) {
  unsigned int u = __float_as_uint(f);
  u += 0x7FFFu + ((u >> 16) & 1u);
  return (unsigned short)(u >> 16);
}
__device__ __forceinline__ float b2f(unsigned short u) {
  return __uint_as_float(((unsigned int)u) << 16);
}

__device__ __forceinline__ void gld_lds16(const unsigned short* g, unsigned short* l) {
  __builtin_amdgcn_global_load_lds(
      (const __attribute__((address_space(1))) unsigned int*)(const void*)g,
      (__attribute__((address_space(3))) unsigned int*)(void*)l, 16, 0, 0);
}

// ---------------- zero fill ----------------
__global__ __launch_bounds__(256) void zero_k(float* __restrict__ p, size_t n) {
  size_t i = ((size_t)blockIdx.x * 256 + threadIdx.x) * 4;
  if (i + 3 < n) {
    *(float4*)&p[i] = make_float4(0.f, 0.f, 0.f, 0.f);
  } else {
    for (; i < n; i++) p[i] = 0.f;
  }
}

// ---------------- f32 -> bf16 ----------------
__global__ __launch_bounds__(256) void cvt_k(const float* __restrict__ in,
                                             unsigned short* __restrict__ out, size_t n) {
  size_t i = ((size_t)blockIdx.x * 256 + threadIdx.x) * 4;
  if (i + 3 < n) {
    const float4 v = *(const float4*)&in[i];
    ushort4 o; o.x = f2b(v.x); o.y = f2b(v.y); o.z = f2b(v.z); o.w = f2b(v.w);
    *(ushort4*)&out[i] = o;
  } else {
    for (; i < n; i++) out[i] = f2b(in[i]);
  }
}

// ---------------- copy bf16 rows into stride-ldo buffer ----------------
__global__ __launch_bounds__(256) void cpy16_k(const unsigned short* __restrict__ in,
                                               unsigned short* __restrict__ out,
                                               int rows, int ldo) {
  size_t gid = (size_t)blockIdx.x * 256 + threadIdx.x;
  size_t idx = gid * 4;
  if (idx >= (size_t)rows * HID) return;
  int row = (int)(idx >> 9);
  int col = (int)(idx & (HID - 1));
  *(ushort4*)&out[(size_t)row * ldo + col] = *(const ushort4*)&in[idx];
}

// ---------------- transpose + cvt: Wt[n*ldo + k] = bf16(W[k*ldw + n]) ----------------
__global__ void tcvt_k(const float* __restrict__ W, unsigned short* __restrict__ Wt,
                       int K, int NC, int ldw, int ldo) {
  __shared__ float tile[32][33];
  const int n0 = blockIdx.x * 32, k0 = blockIdx.y * 32;
  const int tx = threadIdx.x, ty = threadIdx.y;  // 32 x 8
  #pragma unroll
  for (int i = 0; i < 32; i += 8) {
    int k = k0 + ty + i, n = n0 + tx;
    tile[ty + i][tx] = (k < K && n < NC) ? W[(size_t)k * ldw + n] : 0.f;
  }
  __syncthreads();
  #pragma unroll
  for (int i = 0; i < 32; i += 8) {
    int n = n0 + ty + i, k = k0 + tx;
    if (n < NC && k < K) Wt[(size_t)n * ldo + k] = f2b(tile[tx][ty + i]);
  }
}

// ---------------- CSR build ----------------
__global__ __launch_bounds__(256) void hist_k(const int* __restrict__ dst,
                                              int* __restrict__ counts) {
  int e = blockIdx.x * 256 + threadIdx.x;
  if (e < N_EDGES) atomicAdd(&counts[dst[e]], 1);
}

__global__ __launch_bounds__(1024) void scan_k(const int* __restrict__ counts,
                                               int* __restrict__ offsets,
                                               int* __restrict__ pos, int n) {
  __shared__ int tmp[1024];
  __shared__ int carry_s;
  const int tid = threadIdx.x;
  if (tid == 0) carry_s = 0;
  __syncthreads();
  for (int base = 0; base < n; base += 1024) {
    int i = base + tid;
    int v = (i < n) ? counts[i] : 0;
    tmp[tid] = v;
    __syncthreads();
    #pragma unroll
    for (int off = 1; off < 1024; off <<= 1) {
      int t = (tid >= off) ? tmp[tid - off] : 0;
      __syncthreads();
      tmp[tid] += t;
      __syncthreads();
    }
    if (i < n) {
      int excl = carry_s + tmp[tid] - v;
      offsets[i] = excl;
      pos[i] = excl;
    }
    __syncthreads();
    if (tid == 1023) carry_s += tmp[1023];
    __syncthreads();
  }
  if (tid == 0) offsets[n] = carry_s;
}

__global__ __launch_bounds__(256) void fill_k(
    const int* __restrict__ src, const int* __restrict__ dst,
    const float* __restrict__ ew, int* __restrict__ pos,
    int* __restrict__ s_s, float* __restrict__ w_s) {
  int e = blockIdx.x * 256 + threadIdx.x;
  if (e >= N_EDGES) return;
  int p = atomicAdd(&pos[dst[e]], 1);
  s_s[p] = src[e];
  w_s[p] = ew[e];
}

// ---------------- aggregation gather (bf16 XW, fp32 accumulate) ----------------
__global__ __launch_bounds__(128) void gather_k(
    const unsigned short* __restrict__ XW, const int* __restrict__ offsets,
    const int* __restrict__ s_s, const float* __restrict__ w_s,
    float* __restrict__ H) {
  const int n = blockIdx.x;
  const int t = threadIdx.x;
  const int beg = offsets[n], end = offsets[n + 1];
  float4 acc = make_float4(0.f, 0.f, 0.f, 0.f);
  for (int i = beg; i < end; i++) {
    const int   s = s_s[i];
    const float w = w_s[i];
    const ushort4 v = *(const ushort4*)&XW[(size_t)s * HID + t * 4];
    acc.x = fmaf(w, b2f(v.x), acc.x);
    acc.y = fmaf(w, b2f(v.y), acc.y);
    acc.z = fmaf(w, b2f(v.z), acc.z);
    acc.w = fmaf(w, b2f(v.w), acc.w);
  }
  *(float4*)&H[(size_t)n * HID + t * 4] = acc;
}

// ---------------- bf16 MFMA GEMM, bank-conflict-free swizzled LDS ----------------
// C(f32) or C16(bf16) [M,NC] (+)= A[M,K](bf16) * Bt[NC,K](bf16)^T (+bias)
// 128x128 tile, BK=32. LDS chunk swizzle: row r's k-chunk kq stored at slot
// (kq + (r>>1)) & 3  ->  fragment reads are 2-way (free) instead of 8-way.
__global__ __launch_bounds__(256) void gemm_bf16_k(
    const unsigned short* __restrict__ A, const unsigned short* __restrict__ Bt,
    float* __restrict__ C, unsigned short* __restrict__ C16,
    const float* __restrict__ bias,
    int M, int K, int NC, int ldc, int acc)
{
  __shared__ unsigned short As[128 * 32];
  __shared__ unsigned short Bs[128 * 32];
  const int row0 = blockIdx.x * 128;
  const int col0 = blockIdx.y * 128;
  const int t    = threadIdx.x;
  const int lane = t & 63;
  const int w    = t >> 6;
  const int wr   = w >> 1, wc = w & 1;
  const int q    = lane >> 4;
  const int l16  = lane & 15;

  f32x4 accr[4][4] = {};

  for (int k0 = 0; k0 < K; k0 += 32) {
    // stage: LDS slot s (= wave base + lane) holds row r=s>>2, chunk position cq=s&3;
    // the global chunk placed there is kq = (cq - (r>>1)) & 3.
    #pragma unroll
    for (int i = 0; i < 2; i++) {
      int s  = w * 64 + lane + i * 256;
      int r  = s >> 2, cq = s & 3;
      int kq = (cq - (r >> 1)) & 3;
      int gr = row0 + r; if (gr > M - 1) gr = M - 1;
      gld_lds16(A + (size_t)gr * K + k0 + kq * 8, As + (size_t)(w * 64 + i * 256) * 8);
    }
    #pragma unroll
    for (int i = 0; i < 2; i++) {
      int s  = w * 64 + lane + i * 256;
      int r  = s >> 2, cq = s & 3;
      int kq = (cq - (r >> 1)) & 3;
      gld_lds16(Bt + (size_t)(col0 + r) * K + k0 + kq * 8, Bs + (size_t)(w * 64 + i * 256) * 8);
    }
    __syncthreads();

    bf16x8 af[4], bf[4];
    #pragma unroll
    for (int mi = 0; mi < 4; mi++) {
      int r = wr * 64 + mi * 16 + l16;
      int qs = (q + (r >> 1)) & 3;
      af[mi] = *(const bf16x8*)&As[r * 32 + qs * 8];
    }
    #pragma unroll
    for (int ni = 0; ni < 4; ni++) {
      int r = wc * 64 + ni * 16 + l16;
      int qs = (q + (r >> 1)) & 3;
      bf[ni] = *(const bf16x8*)&Bs[r * 32 + qs * 8];
    }
    #pragma unroll
    for (int mi = 0; mi < 4; mi++)
      #pragma unroll
      for (int ni = 0; ni < 4; ni++)
        accr[mi][ni] = __builtin_amdgcn_mfma_f32_16x16x32_bf16(
            af[mi], bf[ni], accr[mi][ni], 0, 0, 0);
    __syncthreads();
  }

  #pragma unroll
  for (int mi = 0; mi < 4; mi++) {
    #pragma unroll
    for (int ni = 0; ni < 4; ni++) {
      int col = col0 + wc * 64 + ni * 16 + l16;
      #pragma unroll
      for (int r = 0; r < 4; r++) {
        int row = row0 + wr * 64 + mi * 16 + q * 4 + r;
        if (row < M) {
          float v = accr[mi][ni][r];
          if (C16) {
            C16[(size_t)row * ldc + col] = f2b(v);
          } else {
            float* cp = &C[(size_t)row * ldc + col];
            if (acc)       *cp += v;
            else if (bias) *cp  = v + bias[col];
            else           *cp  = v;
          }
        }
      }
    }
  }
}

// ---------------- BN stats ----------------
__global__ __launch_bounds__(256) void bn_stats_k(
    const float* __restrict__ H, float* __restrict__ stats, int N)
{
  const int tx = threadIdx.x & 63;
  const int ty = threadIdx.x >> 6;
  const int col = blockIdx.x * 64 + tx;
  float s1 = 0.f, s2 = 0.f;
  for (int r = blockIdx.y * 4 + ty; r < N; r += gridDim.y * 4) {
    float v = H[(size_t)r * HID + col];
    s1 += v; s2 += v * v;
  }
  __shared__ float red[2][4][64];
  red[0][ty][tx] = s1;
  red[1][ty][tx] = s2;
  __syncthreads();
  if (ty == 0) {
    s1 = red[0][0][tx] + red[0][1][tx] + red[0][2][tx] + red[0][3][tx];
    s2 = red[1][0][tx] + red[1][1][tx] + red[1][2][tx] + red[1][3][tx];
    atomicAdd(&stats[col], s1);
    atomicAdd(&stats[HID + col], s2);
  }
}

// ---------------- BN apply + ReLU -> bf16 ----------------
__global__ __launch_bounds__(256) void bn_apply_k(
    const float* __restrict__ H, const float* __restrict__ stats,
    const float* __restrict__ gamma, const float* __restrict__ beta,
    unsigned short* __restrict__ out, int N)
{
  size_t gid = (size_t)blockIdx.x * 256 + threadIdx.x;
  size_t idx = gid * 4;
  if (idx >= (size_t)N * HID) return;
  int col = (int)(idx & (HID - 1));
  const float4 v = *(const float4*)&H[idx];
  float r[4] = {v.x, v.y, v.z, v.w};
  ushort4 o;
  unsigned short* op = &o.x;
  #pragma unroll
  for (int i = 0; i < 4; i++) {
    int c = col + i;
    float mean = stats[c] * (1.0f / N);
    float var  = stats[HID + c] * (1.0f / N) - mean * mean;
    float scale = gamma[c] / sqrtf(var + BN_EPS);
    float shift = beta[c] - mean * scale;
    op[i] = f2b(fmaxf(fmaf(r[i], scale, shift), 0.0f));
  }
  *(ushort4*)&out[idx] = o;
}

// ---------------- LSTM cell part 1 ----------------
__global__ __launch_bounds__(256) void cell1_k(
    const float* __restrict__ gates, const float* __restrict__ cin,
    float* __restrict__ cout, unsigned short* __restrict__ cout16,
    int rows, int hasC)
{
  size_t gid = (size_t)blockIdx.x * 256 + threadIdx.x;
  if (gid >= (size_t)rows * HID) return;
  size_t row = gid >> 9;
  int    col = (int)(gid & (HID - 1));
  const float* g = &gates[row * G4];
  float ig = sigmoidf_(g[col]);
  float gg = tanhf(g[2 * HID + col]);
  float c;
  if (hasC) {
    float fg = sigmoidf_(g[HID + col]);
    c = fg * cin[gid] + ig * gg;
  } else {
    c = ig * gg;
  }
  cout[gid] = c;
  cout16[gid] = f2b(c);
}

// ---------------- LSTM cell part 2 ----------------
__global__ __launch_bounds__(256) void cell2_k(
    const float* __restrict__ gates, const float* __restrict__ cy,
    float* __restrict__ hy, unsigned short* __restrict__ hy16, int ld16, int rows)
{
  size_t gid = (size_t)blockIdx.x * 256 + threadIdx.x;
  if (gid >= (size_t)rows * HID) return;
  size_t row = gid >> 9;
  int    col = (int)(gid & (HID - 1));
  float og = sigmoidf_(gates[row * G4 + 3 * HID + col]);
  float h = og * tanhf(cy[gid]);
  hy[gid] = h;
  if (hy16) hy16[row * ld16 + col] = f2b(h);
}

// ---------------- output projection ----------------
__global__ __launch_bounds__(256) void out_k(
    const float* __restrict__ Hh, const float* __restrict__ W,
    const float* __restrict__ b, float* __restrict__ out, int rows)
{
  int wave = (int)(((size_t)blockIdx.x * 256 + threadIdx.x) >> 6);
  int lane = threadIdx.x & 63;
  if (wave >= rows) return;
  const float* hr = &Hh[(size_t)wave * HID];
  float acc[12] = {};
  for (int k = lane; k < HID; k += 64) {
    float hv = hr[k];
    const float* wr = &W[k * 12];
    #pragma unroll
    for (int p = 0; p < 12; p++) acc[p] = fmaf(hv, wr[p], acc[p]);
  }
  #pragma unroll
  for (int p = 0; p < 12; p++) {
    float v = acc[p];
    #pragma unroll
    for (int off = 32; off > 0; off >>= 1) v += __shfl_down(v, off);
    if (lane == 0) out[(size_t)wave * 12 + p] = v + b[p];
  }
}

extern "C" void kernel_launch(void* const* d_in, const int* in_sizes, int n_in,
                              void* d_out, int out_size, void* d_ws, size_t ws_size,
                              hipStream_t stream) {
  const float* x     = (const float*)d_in[0];
  const int*   ei    = (const int*)d_in[1];
  const float* ew    = (const float*)d_in[2];
  const float* gcn0W = (const float*)d_in[3];
  const float* gcnW  = (const float*)d_in[5];
  const float* gamma = (const float*)d_in[7];
  const float* beta  = (const float*)d_in[8];
  const float* wih   = (const float*)d_in[9];
  const float* whh   = (const float*)d_in[10];
  const float* wch   = (const float*)d_in[11];
  const float* lstmb = (const float*)d_in[12];
  const float* outW  = (const float*)d_in[13];
  const float* outb  = (const float*)d_in[14];
  float* out = (float*)d_out;

  const int* src = ei;
  const int* dst = ei + N_EDGES;

  const int CH = (ws_size >= (size_t)215000000) ? 10000 : 5000;
  const int NCHUNK = N_NODES / CH;

  // -------- workspace layout --------
  const size_t NH = (size_t)N_NODES * HID;
  float* ws = (float*)d_ws;
  float* gates = ws;                                 // CH*2048 fp32
  float* bufH  = gates + (size_t)CH * G4;            // NH fp32
  unsigned short* hbA16 = (unsigned short*)(bufH + NH);
  unsigned short* hbB16 = hbA16 + NH;
  unsigned short* x16   = hbB16 + NH;
  unsigned short* g0t   = x16 + (size_t)N_NODES * IN_CH;
  unsigned short* g1t   = g0t   + 512 * 64;
  unsigned short* g2t   = g1t   + 512 * 512;
  unsigned short* wih0t = g2t   + 512 * 512;             // [2048,512]
  unsigned short* wcat  = wih0t + (size_t)2048 * 512;    // [2048,1024]
  unsigned short* wch0ot= wcat  + (size_t)2048 * 1024;   // [512,512]
  unsigned short* wgf   = wch0ot + 512 * 512;            // [1024,512]
  unsigned short* wch1o = wgf   + (size_t)1024 * 512;    // [512,512]
  unsigned short* wend  = wch1o + 512 * 512;
  unsigned short *a16, *cb16, *tail16;
  if (CH == 5000) {
    a16  = hbB16;
    cb16 = hbB16 + (size_t)CH * 1024;
    tail16 = wend;
  } else {
    a16  = wend;
    cb16 = a16 + (size_t)CH * 1024;
    tail16 = cb16 + (size_t)CH * HID;
  }
  float* stats = (float*)tail16;
  int*   csr   = (int*)(stats + 1024);
  int*   counts  = csr;
  int*   offsets = csr + 20032;
  int*   cpos    = csr + 40064;
  int*   s_s     = csr + 60096;
  float* w_s     = (float*)(csr + 380096);

  float* cbuf = bufH;
  float* hbuf = bufH + (size_t)CH * HID;

  const dim3 blk(256);
  auto gemm = [&](const unsigned short* A, const unsigned short* Bt, float* C,
                  unsigned short* C16, const float* bias,
                  int M, int K, int NC, int ldc, int acc) {
    dim3 grid((M + 127) / 128, NC / 128);
    hipLaunchKernelGGL(gemm_bf16_k, grid, blk, 0, stream, A, Bt, C, C16, bias,
                       M, K, NC, ldc, acc);
  };
  auto tcvt = [&](const float* W, unsigned short* Wt, int K, int NC, int ldw, int ldo) {
    dim3 grid((NC + 31) / 32, (K + 31) / 32);
    hipLaunchKernelGGL(tcvt_k, grid, dim3(32, 8), 0, stream, W, Wt, K, NC, ldw, ldo);
  };
  auto zero = [&](float* p, size_t n) {
    hipLaunchKernelGGL(zero_k, dim3((unsigned)((n / 4 + 255) / 256)), blk, 0, stream, p, n);
  };

  // -------- weight prep --------
  const float* wih1 = wih + (size_t)HID * G4;
  const float* whh1 = whh + (size_t)HID * G4;
  const float* wch1 = wch + (size_t)HID * 3 * HID;
  tcvt(gcn0W, g0t, IN_CH, HID, HID, IN_CH);
  tcvt(gcnW,                     g1t, HID, HID, HID, HID);
  tcvt(gcnW + (size_t)HID * HID, g2t, HID, HID, HID, HID);
  tcvt(wih,  wih0t, HID, G4, G4, HID);
  tcvt(wih1, wcat,       HID, G4, G4, 1024);
  tcvt(whh1, wcat + 512, HID, G4, G4, 1024);
  tcvt(wch + 2 * HID, wch0ot, HID, HID, 3 * HID, HID);
  tcvt(wch1 + HID, wgf,             HID, HID, 3 * HID, HID);
  tcvt(wch1,       wgf + 512 * 512, HID, HID, 3 * HID, HID);
  tcvt(wch1 + 2 * HID, wch1o, HID, HID, 3 * HID, HID);
  hipLaunchKernelGGL(cvt_k, dim3((N_NODES * IN_CH / 4 + 255) / 256), blk, 0, stream,
                     x, x16, (size_t)N_NODES * IN_CH);

  // -------- CSR build --------
  const int e_blocks = (N_EDGES + 255) / 256;
  zero((float*)counts, N_NODES);
  hipLaunchKernelGGL(hist_k, dim3(e_blocks), blk, 0, stream, dst, counts);
  hipLaunchKernelGGL(scan_k, dim3(1), dim3(1024), 0, stream, counts, offsets, cpos, N_NODES);
  hipLaunchKernelGGL(fill_k, dim3(e_blocks), blk, 0, stream, src, dst, ew, cpos, s_s, w_s);

  // -------- GCN stack --------
  const unsigned short* gWt[3] = {g0t, g1t, g2t};
  const int             gK[3]  = {IN_CH, HID, HID};
  const unsigned short* gA[3]  = {x16, hbA16, hbB16};
  unsigned short*       gO[3]  = {hbA16, hbB16, hbA16};
  unsigned short*       gXW[3] = {hbB16, hbB16, hbA16};
  for (int l = 0; l < 3; l++) {
    gemm(gA[l], gWt[l], nullptr, gXW[l], nullptr, N_NODES, gK[l], HID, HID, 0);
    hipLaunchKernelGGL(gather_k, dim3(N_NODES), dim3(128), 0, stream,
                       gXW[l], offsets, s_s, w_s, bufH);
    zero(stats, 2 * HID);
    hipLaunchKernelGGL(bn_stats_k, dim3(8, 64), blk, 0, stream, bufH, stats, N_NODES);
    hipLaunchKernelGGL(bn_apply_k, dim3((unsigned)(NH / 4 / 256)), blk, 0, stream,
                       bufH, stats, gamma + l * HID, beta + l * HID, gO[l], N_NODES);
  }
  unsigned short* hfin16 = hbA16;

  // -------- LSTM + output, chunked --------
  for (int ci = 0; ci < NCHUNK; ci++) {
    const int r0 = ci * CH;
    const unsigned short* h_c = hfin16 + (size_t)r0 * HID;
    const int cell_blocks = (int)(((size_t)CH * HID + 255) / 256);
    const int cpy_blocks  = (int)(((size_t)CH * HID / 4 + 255) / 256);

    hipLaunchKernelGGL(cpy16_k, dim3(cpy_blocks), blk, 0, stream, h_c, a16, CH, 1024);

    // layer 0 (h=c=0)
    gemm(h_c, wih0t, gates, nullptr, lstmb, CH, HID, G4, G4, 0);
    hipLaunchKernelGGL(cell1_k, dim3(cell_blocks), blk, 0, stream,
                       gates, (const float*)nullptr, cbuf, cb16, CH, 0);
    gemm(cb16, wch0ot, gates + 3 * HID, nullptr, nullptr, CH, HID, HID, G4, 1);
    hipLaunchKernelGGL(cell2_k, dim3(cell_blocks), blk, 0, stream,
                       gates, cbuf, hbuf, a16 + HID, 1024, CH);

    // layer 1
    gemm(a16, wcat, gates, nullptr, lstmb + G4, CH, 1024, G4, G4, 0);
    gemm(cb16, wgf, gates + HID, nullptr, nullptr, CH, HID, 1024, G4, 1);
    hipLaunchKernelGGL(cell1_k, dim3(cell_blocks), blk, 0, stream,
                       gates, cbuf, cbuf, cb16, CH, 1);
    gemm(cb16, wch1o, gates + 3 * HID, nullptr, nullptr, CH, HID, HID, G4, 1);
    hipLaunchKernelGGL(cell2_k, dim3(cell_blocks), blk, 0, stream,
                       gates, cbuf, hbuf, (unsigned short*)nullptr, 0, CH);

    hipLaunchKernelGGL(out_k, dim3((CH * 64 + 255) / 256), blk, 0, stream,
                       hbuf, outW, outb, out + (size_t)r0 * 12, CH);
  }
}

// Round 7
// 1132.295 us; speedup vs baseline: 1.0582x; 1.0582x over previous
//
#include <hip/hip_runtime.h>
#include <cstddef>

#define N_NODES 20000
#define N_EDGES 320000
#define IN_CH   64
#define HID     512
#define G4      2048
#define BN_EPS  1e-5f

typedef __attribute__((ext_vector_type(8))) __bf16 bf16x8;
typedef __attribute__((ext_vector_type(4))) float f32x4;

__device__ __forceinline__ float sigmoidf_(float x) {
  return 1.0f / (1.0f + expf(-x));
}

// fp32 -> bf16 (RNE)
__device__ __forceinline__ unsigned short f2b(float f) {
  unsigned int u = __float_as_uint(f);
  u += 0x7FFFu + ((u >> 16) & 1u);
  return (unsigned short)(u >> 16);
}
__device__ __forceinline__ float b2f(unsigned short u) {
  return __uint_as_float(((unsigned int)u) << 16);
}

__device__ __forceinline__ void gld_lds16(const unsigned short* g, unsigned short* l) {
  __builtin_amdgcn_global_load_lds(
      (const __attribute__((address_space(1))) unsigned int*)(const void*)g,
      (__attribute__((address_space(3))) unsigned int*)(void*)l, 16, 0, 0);
}

// ---------------- zero fill ----------------
__global__ __launch_bounds__(256) void zero_k(float* __restrict__ p, size_t n) {
  size_t i = ((size_t)blockIdx.x * 256 + threadIdx.x) * 4;
  if (i + 3 < n) {
    *(float4*)&p[i] = make_float4(0.f, 0.f, 0.f, 0.f);
  } else {
    for (; i < n; i++) p[i] = 0.f;
  }
}

// ---------------- f32 -> bf16 ----------------
__global__ __launch_bounds__(256) void cvt_k(const float* __restrict__ in,
                                             unsigned short* __restrict__ out, size_t n) {
  size_t i = ((size_t)blockIdx.x * 256 + threadIdx.x) * 4;
  if (i + 3 < n) {
    const float4 v = *(const float4*)&in[i];
    ushort4 o; o.x = f2b(v.x); o.y = f2b(v.y); o.z = f2b(v.z); o.w = f2b(v.w);
    *(ushort4*)&out[i] = o;
  } else {
    for (; i < n; i++) out[i] = f2b(in[i]);
  }
}

// ---------------- copy bf16 rows into stride-ldo buffer ----------------
__global__ __launch_bounds__(256) void cpy16_k(const unsigned short* __restrict__ in,
                                               unsigned short* __restrict__ out,
                                               int rows, int ldo) {
  size_t gid = (size_t)blockIdx.x * 256 + threadIdx.x;
  size_t idx = gid * 4;
  if (idx >= (size_t)rows * HID) return;
  int row = (int)(idx >> 9);
  int col = (int)(idx & (HID - 1));
  *(ushort4*)&out[(size_t)row * ldo + col] = *(const ushort4*)&in[idx];
}

// ---------------- transpose + cvt: Wt[n*ldo + k] = bf16(W[k*ldw + n]) ----------------
__global__ void tcvt_k(const float* __restrict__ W, unsigned short* __restrict__ Wt,
                       int K, int NC, int ldw, int ldo) {
  __shared__ float tile[32][33];
  const int n0 = blockIdx.x * 32, k0 = blockIdx.y * 32;
  const int tx = threadIdx.x, ty = threadIdx.y;  // 32 x 8
  #pragma unroll
  for (int i = 0; i < 32; i += 8) {
    int k = k0 + ty + i, n = n0 + tx;
    tile[ty + i][tx] = (k < K && n < NC) ? W[(size_t)k * ldw + n] : 0.f;
  }
  __syncthreads();
  #pragma unroll
  for (int i = 0; i < 32; i += 8) {
    int n = n0 + ty + i, k = k0 + tx;
    if (n < NC && k < K) Wt[(size_t)n * ldo + k] = f2b(tile[tx][ty + i]);
  }
}

// ---------------- CSR build ----------------
__global__ __launch_bounds__(256) void hist_k(const int* __restrict__ dst,
                                              int* __restrict__ counts) {
  int e = blockIdx.x * 256 + threadIdx.x;
  if (e < N_EDGES) atomicAdd(&counts[dst[e]], 1);
}

__global__ __launch_bounds__(1024) void scan_k(const int* __restrict__ counts,
                                               int* __restrict__ offsets,
                                               int* __restrict__ pos, int n) {
  __shared__ int tmp[1024];
  __shared__ int carry_s;
  const int tid = threadIdx.x;
  if (tid == 0) carry_s = 0;
  __syncthreads();
  for (int base = 0; base < n; base += 1024) {
    int i = base + tid;
    int v = (i < n) ? counts[i] : 0;
    tmp[tid] = v;
    __syncthreads();
    #pragma unroll
    for (int off = 1; off < 1024; off <<= 1) {
      int t = (tid >= off) ? tmp[tid - off] : 0;
      __syncthreads();
      tmp[tid] += t;
      __syncthreads();
    }
    if (i < n) {
      int excl = carry_s + tmp[tid] - v;
      offsets[i] = excl;
      pos[i] = excl;
    }
    __syncthreads();
    if (tid == 1023) carry_s += tmp[1023];
    __syncthreads();
  }
  if (tid == 0) offsets[n] = carry_s;
}

__global__ __launch_bounds__(256) void fill_k(
    const int* __restrict__ src, const int* __restrict__ dst,
    const float* __restrict__ ew, int* __restrict__ pos,
    int* __restrict__ s_s, float* __restrict__ w_s) {
  int e = blockIdx.x * 256 + threadIdx.x;
  if (e >= N_EDGES) return;
  int p = atomicAdd(&pos[dst[e]], 1);
  s_s[p] = src[e];
  w_s[p] = ew[e];
}

// ---------------- aggregation gather (bf16 XW, fp32 accumulate) ----------------
__global__ __launch_bounds__(128) void gather_k(
    const unsigned short* __restrict__ XW, const int* __restrict__ offsets,
    const int* __restrict__ s_s, const float* __restrict__ w_s,
    float* __restrict__ H) {
  const int n = blockIdx.x;
  const int t = threadIdx.x;
  const int beg = offsets[n], end = offsets[n + 1];
  float4 acc = make_float4(0.f, 0.f, 0.f, 0.f);
  for (int i = beg; i < end; i++) {
    const int   s = s_s[i];
    const float w = w_s[i];
    const ushort4 v = *(const ushort4*)&XW[(size_t)s * HID + t * 4];
    acc.x = fmaf(w, b2f(v.x), acc.x);
    acc.y = fmaf(w, b2f(v.y), acc.y);
    acc.z = fmaf(w, b2f(v.z), acc.z);
    acc.w = fmaf(w, b2f(v.w), acc.w);
  }
  *(float4*)&H[(size_t)n * HID + t * 4] = acc;
}

// ---------------- bf16 MFMA GEMM, swizzled LDS + XCD-aware block mapping --------
// C(f32) or C16(bf16) [M,NC] (+)= A[M,K](bf16) * Bt[NC,K](bf16)^T (+bias)
// 1D grid; block b -> xcd=b&7, j=b>>3; col=j%ncolb, row=(j/ncolb)*8+xcd.
// Each XCD owns row-strips r%8==xcd across ALL column-blocks consecutively:
// A fetched once device-wide, per-XCD B working set stays L2-resident.
__global__ __launch_bounds__(256) void gemm_bf16_k(
    const unsigned short* __restrict__ A, const unsigned short* __restrict__ Bt,
    float* __restrict__ C, unsigned short* __restrict__ C16,
    const float* __restrict__ bias,
    int M, int K, int NC, int ldc, int acc, int nrowb, int ncolb)
{
  const int b   = blockIdx.x;
  const int xcd = b & 7;
  const int j   = b >> 3;
  const int col_b = j % ncolb;
  const int row_b = (j / ncolb) * 8 + xcd;
  if (row_b >= nrowb) return;

  __shared__ unsigned short As[128 * 32];
  __shared__ unsigned short Bs[128 * 32];
  const int row0 = row_b * 128;
  const int col0 = col_b * 128;
  const int t    = threadIdx.x;
  const int lane = t & 63;
  const int w    = t >> 6;
  const int wr   = w >> 1, wc = w & 1;
  const int q    = lane >> 4;
  const int l16  = lane & 15;

  f32x4 accr[4][4] = {};

  for (int k0 = 0; k0 < K; k0 += 32) {
    // swizzled staging: LDS slot s holds row r=s>>2, chunk pos cq=s&3,
    // sourced from global chunk kq=(cq-(r>>1))&3.
    #pragma unroll
    for (int i = 0; i < 2; i++) {
      int s  = w * 64 + lane + i * 256;
      int r  = s >> 2, cq = s & 3;
      int kq = (cq - (r >> 1)) & 3;
      int gr = row0 + r; if (gr > M - 1) gr = M - 1;
      gld_lds16(A + (size_t)gr * K + k0 + kq * 8, As + (size_t)(w * 64 + i * 256) * 8);
    }
    #pragma unroll
    for (int i = 0; i < 2; i++) {
      int s  = w * 64 + lane + i * 256;
      int r  = s >> 2, cq = s & 3;
      int kq = (cq - (r >> 1)) & 3;
      gld_lds16(Bt + (size_t)(col0 + r) * K + k0 + kq * 8, Bs + (size_t)(w * 64 + i * 256) * 8);
    }
    __syncthreads();

    bf16x8 af[4], bf[4];
    #pragma unroll
    for (int mi = 0; mi < 4; mi++) {
      int r = wr * 64 + mi * 16 + l16;
      int qs = (q + (r >> 1)) & 3;
      af[mi] = *(const bf16x8*)&As[r * 32 + qs * 8];
    }
    #pragma unroll
    for (int ni = 0; ni < 4; ni++) {
      int r = wc * 64 + ni * 16 + l16;
      int qs = (q + (r >> 1)) & 3;
      bf[ni] = *(const bf16x8*)&Bs[r * 32 + qs * 8];
    }
    #pragma unroll
    for (int mi = 0; mi < 4; mi++)
      #pragma unroll
      for (int ni = 0; ni < 4; ni++)
        accr[mi][ni] = __builtin_amdgcn_mfma_f32_16x16x32_bf16(
            af[mi], bf[ni], accr[mi][ni], 0, 0, 0);
    __syncthreads();
  }

  #pragma unroll
  for (int mi = 0; mi < 4; mi++) {
    #pragma unroll
    for (int ni = 0; ni < 4; ni++) {
      int col = col0 + wc * 64 + ni * 16 + l16;
      #pragma unroll
      for (int r = 0; r < 4; r++) {
        int row = row0 + wr * 64 + mi * 16 + q * 4 + r;
        if (row < M) {
          float v = accr[mi][ni][r];
          if (C16) {
            C16[(size_t)row * ldc + col] = f2b(v);
          } else {
            float* cp = &C[(size_t)row * ldc + col];
            if (acc)       *cp += v;
            else if (bias) *cp  = v + bias[col];
            else           *cp  = v;
          }
        }
      }
    }
  }
}

// ---------------- BN stats ----------------
__global__ __launch_bounds__(256) void bn_stats_k(
    const float* __restrict__ H, float* __restrict__ stats, int N)
{
  const int tx = threadIdx.x & 63;
  const int ty = threadIdx.x >> 6;
  const int col = blockIdx.x * 64 + tx;
  float s1 = 0.f, s2 = 0.f;
  for (int r = blockIdx.y * 4 + ty; r < N; r += gridDim.y * 4) {
    float v = H[(size_t)r * HID + col];
    s1 += v; s2 += v * v;
  }
  __shared__ float red[2][4][64];
  red[0][ty][tx] = s1;
  red[1][ty][tx] = s2;
  __syncthreads();
  if (ty == 0) {
    s1 = red[0][0][tx] + red[0][1][tx] + red[0][2][tx] + red[0][3][tx];
    s2 = red[1][0][tx] + red[1][1][tx] + red[1][2][tx] + red[1][3][tx];
    atomicAdd(&stats[col], s1);
    atomicAdd(&stats[HID + col], s2);
  }
}

// ---------------- BN apply + ReLU -> bf16 ----------------
__global__ __launch_bounds__(256) void bn_apply_k(
    const float* __restrict__ H, const float* __restrict__ stats,
    const float* __restrict__ gamma, const float* __restrict__ beta,
    unsigned short* __restrict__ out, int N)
{
  size_t gid = (size_t)blockIdx.x * 256 + threadIdx.x;
  size_t idx = gid * 4;
  if (idx >= (size_t)N * HID) return;
  int col = (int)(idx & (HID - 1));
  const float4 v = *(const float4*)&H[idx];
  float r[4] = {v.x, v.y, v.z, v.w};
  ushort4 o;
  unsigned short* op = &o.x;
  #pragma unroll
  for (int i = 0; i < 4; i++) {
    int c = col + i;
    float mean = stats[c] * (1.0f / N);
    float var  = stats[HID + c] * (1.0f / N) - mean * mean;
    float scale = gamma[c] / sqrtf(var + BN_EPS);
    float shift = beta[c] - mean * scale;
    op[i] = f2b(fmaxf(fmaf(r[i], scale, shift), 0.0f));
  }
  *(ushort4*)&out[idx] = o;
}

// ---------------- LSTM cell part 1 ----------------
__global__ __launch_bounds__(256) void cell1_k(
    const float* __restrict__ gates, const float* __restrict__ cin,
    float* __restrict__ cout, unsigned short* __restrict__ cout16,
    int rows, int hasC)
{
  size_t gid = (size_t)blockIdx.x * 256 + threadIdx.x;
  if (gid >= (size_t)rows * HID) return;
  size_t row = gid >> 9;
  int    col = (int)(gid & (HID - 1));
  const float* g = &gates[row * G4];
  float ig = sigmoidf_(g[col]);
  float gg = tanhf(g[2 * HID + col]);
  float c;
  if (hasC) {
    float fg = sigmoidf_(g[HID + col]);
    c = fg * cin[gid] + ig * gg;
  } else {
    c = ig * gg;
  }
  cout[gid] = c;
  cout16[gid] = f2b(c);
}

// ---------------- LSTM cell part 2 ----------------
__global__ __launch_bounds__(256) void cell2_k(
    const float* __restrict__ gates, const float* __restrict__ cy,
    float* __restrict__ hy, unsigned short* __restrict__ hy16, int ld16, int rows)
{
  size_t gid = (size_t)blockIdx.x * 256 + threadIdx.x;
  if (gid >= (size_t)rows * HID) return;
  size_t row = gid >> 9;
  int    col = (int)(gid & (HID - 1));
  float og = sigmoidf_(gates[row * G4 + 3 * HID + col]);
  float h = og * tanhf(cy[gid]);
  hy[gid] = h;
  if (hy16) hy16[row * ld16 + col] = f2b(h);
}

// ---------------- output projection ----------------
__global__ __launch_bounds__(256) void out_k(
    const float* __restrict__ Hh, const float* __restrict__ W,
    const float* __restrict__ b, float* __restrict__ out, int rows)
{
  int wave = (int)(((size_t)blockIdx.x * 256 + threadIdx.x) >> 6);
  int lane = threadIdx.x & 63;
  if (wave >= rows) return;
  const float* hr = &Hh[(size_t)wave * HID];
  float acc[12] = {};
  for (int k = lane; k < HID; k += 64) {
    float hv = hr[k];
    const float* wr = &W[k * 12];
    #pragma unroll
    for (int p = 0; p < 12; p++) acc[p] = fmaf(hv, wr[p], acc[p]);
  }
  #pragma unroll
  for (int p = 0; p < 12; p++) {
    float v = acc[p];
    #pragma unroll
    for (int off = 32; off > 0; off >>= 1) v += __shfl_down(v, off);
    if (lane == 0) out[(size_t)wave * 12 + p] = v + b[p];
  }
}

extern "C" void kernel_launch(void* const* d_in, const int* in_sizes, int n_in,
                              void* d_out, int out_size, void* d_ws, size_t ws_size,
                              hipStream_t stream) {
  const float* x     = (const float*)d_in[0];
  const int*   ei    = (const int*)d_in[1];
  const float* ew    = (const float*)d_in[2];
  const float* gcn0W = (const float*)d_in[3];
  const float* gcnW  = (const float*)d_in[5];
  const float* gamma = (const float*)d_in[7];
  const float* beta  = (const float*)d_in[8];
  const float* wih   = (const float*)d_in[9];
  const float* whh   = (const float*)d_in[10];
  const float* wch   = (const float*)d_in[11];
  const float* lstmb = (const float*)d_in[12];
  const float* outW  = (const float*)d_in[13];
  const float* outb  = (const float*)d_in[14];
  float* out = (float*)d_out;

  const int* src = ei;
  const int* dst = ei + N_EDGES;

  const int CH = (ws_size >= (size_t)215000000) ? 10000 : 5000;
  const int NCHUNK = N_NODES / CH;

  // -------- workspace layout --------
  const size_t NH = (size_t)N_NODES * HID;
  float* ws = (float*)d_ws;
  float* gates = ws;                                 // CH*2048 fp32
  float* bufH  = gates + (size_t)CH * G4;            // NH fp32
  unsigned short* hbA16 = (unsigned short*)(bufH + NH);
  unsigned short* hbB16 = hbA16 + NH;
  unsigned short* x16   = hbB16 + NH;
  unsigned short* g0t   = x16 + (size_t)N_NODES * IN_CH;
  unsigned short* g1t   = g0t   + 512 * 64;
  unsigned short* g2t   = g1t   + 512 * 512;
  unsigned short* wih0t = g2t   + 512 * 512;             // [2048,512]
  unsigned short* wcat  = wih0t + (size_t)2048 * 512;    // [2048,1024]
  unsigned short* wch0ot= wcat  + (size_t)2048 * 1024;   // [512,512]
  unsigned short* wgf   = wch0ot + 512 * 512;            // [1024,512]
  unsigned short* wch1o = wgf   + (size_t)1024 * 512;    // [512,512]
  unsigned short* wend  = wch1o + 512 * 512;
  unsigned short *a16, *cb16, *tail16;
  if (CH == 5000) {
    a16  = hbB16;
    cb16 = hbB16 + (size_t)CH * 1024;
    tail16 = wend;
  } else {
    a16  = wend;
    cb16 = a16 + (size_t)CH * 1024;
    tail16 = cb16 + (size_t)CH * HID;
  }
  float* stats = (float*)tail16;
  int*   csr   = (int*)(stats + 1024);
  int*   counts  = csr;
  int*   offsets = csr + 20032;
  int*   cpos    = csr + 40064;
  int*   s_s     = csr + 60096;
  float* w_s     = (float*)(csr + 380096);

  float* cbuf = bufH;
  float* hbuf = bufH + (size_t)CH * HID;

  const dim3 blk(256);
  auto gemm = [&](const unsigned short* A, const unsigned short* Bt, float* C,
                  unsigned short* C16, const float* bias,
                  int M, int K, int NC, int ldc, int acc) {
    int nrowb = (M + 127) / 128;
    int ncolb = NC / 128;
    int nblocks = 8 * ((nrowb + 7) / 8) * ncolb;
    hipLaunchKernelGGL(gemm_bf16_k, dim3(nblocks), blk, 0, stream, A, Bt, C, C16, bias,
                       M, K, NC, ldc, acc, nrowb, ncolb);
  };
  auto tcvt = [&](const float* W, unsigned short* Wt, int K, int NC, int ldw, int ldo) {
    dim3 grid((NC + 31) / 32, (K + 31) / 32);
    hipLaunchKernelGGL(tcvt_k, grid, dim3(32, 8), 0, stream, W, Wt, K, NC, ldw, ldo);
  };
  auto zero = [&](float* p, size_t n) {
    hipLaunchKernelGGL(zero_k, dim3((unsigned)((n / 4 + 255) / 256)), blk, 0, stream, p, n);
  };

  // -------- weight prep --------
  const float* wih1 = wih + (size_t)HID * G4;
  const float* whh1 = whh + (size_t)HID * G4;
  const float* wch1 = wch + (size_t)HID * 3 * HID;
  tcvt(gcn0W, g0t, IN_CH, HID, HID, IN_CH);
  tcvt(gcnW,                     g1t, HID, HID, HID, HID);
  tcvt(gcnW + (size_t)HID * HID, g2t, HID, HID, HID, HID);
  tcvt(wih,  wih0t, HID, G4, G4, HID);
  tcvt(wih1, wcat,       HID, G4, G4, 1024);
  tcvt(whh1, wcat + 512, HID, G4, G4, 1024);
  tcvt(wch + 2 * HID, wch0ot, HID, HID, 3 * HID, HID);
  tcvt(wch1 + HID, wgf,             HID, HID, 3 * HID, HID);
  tcvt(wch1,       wgf + 512 * 512, HID, HID, 3 * HID, HID);
  tcvt(wch1 + 2 * HID, wch1o, HID, HID, 3 * HID, HID);
  hipLaunchKernelGGL(cvt_k, dim3((N_NODES * IN_CH / 4 + 255) / 256), blk, 0, stream,
                     x, x16, (size_t)N_NODES * IN_CH);

  // -------- CSR build --------
  const int e_blocks = (N_EDGES + 255) / 256;
  zero((float*)counts, N_NODES);
  hipLaunchKernelGGL(hist_k, dim3(e_blocks), blk, 0, stream, dst, counts);
  hipLaunchKernelGGL(scan_k, dim3(1), dim3(1024), 0, stream, counts, offsets, cpos, N_NODES);
  hipLaunchKernelGGL(fill_k, dim3(e_blocks), blk, 0, stream, src, dst, ew, cpos, s_s, w_s);

  // -------- GCN stack --------
  const unsigned short* gWt[3] = {g0t, g1t, g2t};
  const int             gK[3]  = {IN_CH, HID, HID};
  const unsigned short* gA[3]  = {x16, hbA16, hbB16};
  unsigned short*       gO[3]  = {hbA16, hbB16, hbA16};
  unsigned short*       gXW[3] = {hbB16, hbB16, hbA16};
  for (int l = 0; l < 3; l++) {
    gemm(gA[l], gWt[l], nullptr, gXW[l], nullptr, N_NODES, gK[l], HID, HID, 0);
    hipLaunchKernelGGL(gather_k, dim3(N_NODES), dim3(128), 0, stream,
                       gXW[l], offsets, s_s, w_s, bufH);
    zero(stats, 2 * HID);
    hipLaunchKernelGGL(bn_stats_k, dim3(8, 64), blk, 0, stream, bufH, stats, N_NODES);
    hipLaunchKernelGGL(bn_apply_k, dim3((unsigned)(NH / 4 / 256)), blk, 0, stream,
                       bufH, stats, gamma + l * HID, beta + l * HID, gO[l], N_NODES);
  }
  unsigned short* hfin16 = hbA16;

  // -------- LSTM + output, chunked --------
  for (int ci = 0; ci < NCHUNK; ci++) {
    const int r0 = ci * CH;
    const unsigned short* h_c = hfin16 + (size_t)r0 * HID;
    const int cell_blocks = (int)(((size_t)CH * HID + 255) / 256);
    const int cpy_blocks  = (int)(((size_t)CH * HID / 4 + 255) / 256);

    hipLaunchKernelGGL(cpy16_k, dim3(cpy_blocks), blk, 0, stream, h_c, a16, CH, 1024);

    // layer 0 (h=c=0)
    gemm(h_c, wih0t, gates, nullptr, lstmb, CH, HID, G4, G4, 0);
    hipLaunchKernelGGL(cell1_k, dim3(cell_blocks), blk, 0, stream,
                       gates, (const float*)nullptr, cbuf, cb16, CH, 0);
    gemm(cb16, wch0ot, gates + 3 * HID, nullptr, nullptr, CH, HID, HID, G4, 1);
    hipLaunchKernelGGL(cell2_k, dim3(cell_blocks), blk, 0, stream,
                       gates, cbuf, hbuf, a16 + HID, 1024, CH);

    // layer 1
    gemm(a16, wcat, gates, nullptr, lstmb + G4, CH, 1024, G4, G4, 0);
    gemm(cb16, wgf, gates + HID, nullptr, nullptr, CH, HID, 1024, G4, 1);
    hipLaunchKernelGGL(cell1_k, dim3(cell_blocks), blk, 0, stream,
                       gates, cbuf, cbuf, cb16, CH, 1);
    gemm(cb16, wch1o, gates + 3 * HID, nullptr, nullptr, CH, HID, HID, G4, 1);
    hipLaunchKernelGGL(cell2_k, dim3(cell_blocks), blk, 0, stream,
                       gates, cbuf, hbuf, (unsigned short*)nullptr, 0, CH);

    hipLaunchKernelGGL(out_k, dim3((CH * 64 + 255) / 256), blk, 0, stream,
                       hbuf, outW, outb, out + (size_t)r0 * 12, CH);
  }
}

// Round 8
// 1068.095 us; speedup vs baseline: 1.1218x; 1.0601x over previous
//
#include <hip/hip_runtime.h>
#include <cstddef>

#define N_NODES 20000
#define N_EDGES 320000
#define IN_CH   64
#define HID     512
#define G4      2048
#define BN_EPS  1e-5f

typedef __attribute__((ext_vector_type(8))) __bf16 bf16x8;
typedef __attribute__((ext_vector_type(4))) float f32x4;

__device__ __forceinline__ float sigmoidf_(float x) {
  return 1.0f / (1.0f + expf(-x));
}

// fp32 -> bf16 (RNE)
__device__ __forceinline__ unsigned short f2b(float f) {
  unsigned int u = __float_as_uint(f);
  u += 0x7FFFu + ((u >> 16) & 1u);
  return (unsigned short)(u >> 16);
}
__device__ __forceinline__ float b2f(unsigned short u) {
  return __uint_as_float(((unsigned int)u) << 16);
}

__device__ __forceinline__ void gld_lds16(const unsigned short* g, unsigned short* l) {
  __builtin_amdgcn_global_load_lds(
      (const __attribute__((address_space(1))) unsigned int*)(const void*)g,
      (__attribute__((address_space(3))) unsigned int*)(void*)l, 16, 0, 0);
}

// ---------------- zero fill ----------------
__global__ __launch_bounds__(256) void zero_k(float* __restrict__ p, size_t n) {
  size_t i = ((size_t)blockIdx.x * 256 + threadIdx.x) * 4;
  if (i + 3 < n) {
    *(float4*)&p[i] = make_float4(0.f, 0.f, 0.f, 0.f);
  } else {
    for (; i < n; i++) p[i] = 0.f;
  }
}

// ---------------- f32 -> bf16 ----------------
__global__ __launch_bounds__(256) void cvt_k(const float* __restrict__ in,
                                             unsigned short* __restrict__ out, size_t n) {
  size_t i = ((size_t)blockIdx.x * 256 + threadIdx.x) * 4;
  if (i + 3 < n) {
    const float4 v = *(const float4*)&in[i];
    ushort4 o; o.x = f2b(v.x); o.y = f2b(v.y); o.z = f2b(v.z); o.w = f2b(v.w);
    *(ushort4*)&out[i] = o;
  } else {
    for (; i < n; i++) out[i] = f2b(in[i]);
  }
}

// ---------------- copy bf16 rows into stride-ldo buffer ----------------
__global__ __launch_bounds__(256) void cpy16_k(const unsigned short* __restrict__ in,
                                               unsigned short* __restrict__ out,
                                               int rows, int ldo) {
  size_t gid = (size_t)blockIdx.x * 256 + threadIdx.x;
  size_t idx = gid * 4;
  if (idx >= (size_t)rows * HID) return;
  int row = (int)(idx >> 9);
  int col = (int)(idx & (HID - 1));
  *(ushort4*)&out[(size_t)row * ldo + col] = *(const ushort4*)&in[idx];
}

// ---------------- transpose + cvt: Wt[n*ldo + k] = bf16(W[k*ldw + n]) ----------------
__global__ void tcvt_k(const float* __restrict__ W, unsigned short* __restrict__ Wt,
                       int K, int NC, int ldw, int ldo) {
  __shared__ float tile[32][33];
  const int n0 = blockIdx.x * 32, k0 = blockIdx.y * 32;
  const int tx = threadIdx.x, ty = threadIdx.y;  // 32 x 8
  #pragma unroll
  for (int i = 0; i < 32; i += 8) {
    int k = k0 + ty + i, n = n0 + tx;
    tile[ty + i][tx] = (k < K && n < NC) ? W[(size_t)k * ldw + n] : 0.f;
  }
  __syncthreads();
  #pragma unroll
  for (int i = 0; i < 32; i += 8) {
    int n = n0 + ty + i, k = k0 + tx;
    if (n < NC && k < K) Wt[(size_t)n * ldo + k] = f2b(tile[tx][ty + i]);
  }
}

// ---------------- CSR build ----------------
__global__ __launch_bounds__(256) void hist_k(const int* __restrict__ dst,
                                              int* __restrict__ counts) {
  int e = blockIdx.x * 256 + threadIdx.x;
  if (e < N_EDGES) atomicAdd(&counts[dst[e]], 1);
}

__global__ __launch_bounds__(1024) void scan_k(const int* __restrict__ counts,
                                               int* __restrict__ offsets,
                                               int* __restrict__ pos, int n) {
  __shared__ int tmp[1024];
  __shared__ int carry_s;
  const int tid = threadIdx.x;
  if (tid == 0) carry_s = 0;
  __syncthreads();
  for (int base = 0; base < n; base += 1024) {
    int i = base + tid;
    int v = (i < n) ? counts[i] : 0;
    tmp[tid] = v;
    __syncthreads();
    #pragma unroll
    for (int off = 1; off < 1024; off <<= 1) {
      int t = (tid >= off) ? tmp[tid - off] : 0;
      __syncthreads();
      tmp[tid] += t;
      __syncthreads();
    }
    if (i < n) {
      int excl = carry_s + tmp[tid] - v;
      offsets[i] = excl;
      pos[i] = excl;
    }
    __syncthreads();
    if (tid == 1023) carry_s += tmp[1023];
    __syncthreads();
  }
  if (tid == 0) offsets[n] = carry_s;
}

__global__ __launch_bounds__(256) void fill_k(
    const int* __restrict__ src, const int* __restrict__ dst,
    const float* __restrict__ ew, int* __restrict__ pos,
    int* __restrict__ s_s, float* __restrict__ w_s) {
  int e = blockIdx.x * 256 + threadIdx.x;
  if (e >= N_EDGES) return;
  int p = atomicAdd(&pos[dst[e]], 1);
  s_s[p] = src[e];
  w_s[p] = ew[e];
}

// ---------------- aggregation gather (bf16 XW, fp32 accumulate) ----------------
__global__ __launch_bounds__(128) void gather_k(
    const unsigned short* __restrict__ XW, const int* __restrict__ offsets,
    const int* __restrict__ s_s, const float* __restrict__ w_s,
    float* __restrict__ H) {
  const int n = blockIdx.x;
  const int t = threadIdx.x;
  const int beg = offsets[n], end = offsets[n + 1];
  float4 acc = make_float4(0.f, 0.f, 0.f, 0.f);
  for (int i = beg; i < end; i++) {
    const int   s = s_s[i];
    const float w = w_s[i];
    const ushort4 v = *(const ushort4*)&XW[(size_t)s * HID + t * 4];
    acc.x = fmaf(w, b2f(v.x), acc.x);
    acc.y = fmaf(w, b2f(v.y), acc.y);
    acc.z = fmaf(w, b2f(v.z), acc.z);
    acc.w = fmaf(w, b2f(v.w), acc.w);
  }
  *(float4*)&H[(size_t)n * HID + t * 4] = acc;
}

// ---------------- bf16 MFMA GEMM (templated BN), swizzled LDS + XCD mapping ----
// C(f32) or C16(bf16) [M,NC] (+)= A[M,K](bf16, lda) * Bt[NC,K](bf16)^T (+bias)
// Tile 128 x BN. BN=128: 4 waves of 64x64 (64 AGPR). BN=64: 4 waves of 32x64
// (32 AGPR -> more resident waves; 2x blocks for small NC).
template<int BN>
__global__ __launch_bounds__(256) void gemm_bf16_k(
    const unsigned short* __restrict__ A, const unsigned short* __restrict__ Bt,
    float* __restrict__ C, unsigned short* __restrict__ C16,
    const float* __restrict__ bias,
    int M, int K, int lda, int NC, int ldc, int acc, int nrowb, int ncolb)
{
  const int b   = blockIdx.x;
  const int xcd = b & 7;
  const int j   = b >> 3;
  const int col_b = j % ncolb;
  const int row_b = (j / ncolb) * 8 + xcd;
  if (row_b >= nrowb) return;

  constexpr int MI = (BN == 128) ? 4 : 2;
  __shared__ unsigned short As[128 * 32];
  __shared__ unsigned short Bs[BN * 32];
  const int row0 = row_b * 128;
  const int col0 = col_b * BN;
  const int t    = threadIdx.x;
  const int lane = t & 63;
  const int w    = t >> 6;
  const int wro  = (BN == 128) ? (w >> 1) * 64 : w * 32;  // wave row origin in tile
  const int wco  = (BN == 128) ? (w & 1) * 64 : 0;        // wave col origin in tile
  const int q    = lane >> 4;
  const int l16  = lane & 15;

  f32x4 accr[MI][4] = {};

  for (int k0 = 0; k0 < K; k0 += 32) {
    // swizzled staging: LDS slot s holds row r=s>>2, chunk pos cq=s&3,
    // sourced from global chunk kq=(cq-(r>>1))&3.
    #pragma unroll
    for (int i = 0; i < 2; i++) {
      int s  = t + i * 256;
      int r  = s >> 2, cq = s & 3;
      int kq = (cq - (r >> 1)) & 3;
      int gr = row0 + r; if (gr > M - 1) gr = M - 1;
      gld_lds16(A + (size_t)gr * lda + k0 + kq * 8, As + (size_t)s * 8);
    }
    #pragma unroll
    for (int i = 0; i < BN / 64; i++) {
      int s  = t + i * 256;
      int r  = s >> 2, cq = s & 3;
      int kq = (cq - (r >> 1)) & 3;
      gld_lds16(Bt + (size_t)(col0 + r) * K + k0 + kq * 8, Bs + (size_t)s * 8);
    }
    __syncthreads();

    bf16x8 af[MI], bf[4];
    #pragma unroll
    for (int mi = 0; mi < MI; mi++) {
      int r = wro + mi * 16 + l16;
      int qs = (q + (r >> 1)) & 3;
      af[mi] = *(const bf16x8*)&As[r * 32 + qs * 8];
    }
    #pragma unroll
    for (int ni = 0; ni < 4; ni++) {
      int r = wco + ni * 16 + l16;
      int qs = (q + (r >> 1)) & 3;
      bf[ni] = *(const bf16x8*)&Bs[r * 32 + qs * 8];
    }
    #pragma unroll
    for (int mi = 0; mi < MI; mi++)
      #pragma unroll
      for (int ni = 0; ni < 4; ni++)
        accr[mi][ni] = __builtin_amdgcn_mfma_f32_16x16x32_bf16(
            af[mi], bf[ni], accr[mi][ni], 0, 0, 0);
    __syncthreads();
  }

  #pragma unroll
  for (int mi = 0; mi < MI; mi++) {
    #pragma unroll
    for (int ni = 0; ni < 4; ni++) {
      int col = col0 + wco + ni * 16 + l16;
      #pragma unroll
      for (int r = 0; r < 4; r++) {
        int row = row0 + wro + mi * 16 + q * 4 + r;
        if (row < M) {
          float v = accr[mi][ni][r];
          if (C16) {
            C16[(size_t)row * ldc + col] = f2b(v);
          } else {
            float* cp = &C[(size_t)row * ldc + col];
            if (acc)       *cp += v;
            else if (bias) *cp  = v + bias[col];
            else           *cp  = v;
          }
        }
      }
    }
  }
}

// ---------------- BN stats ----------------
__global__ __launch_bounds__(256) void bn_stats_k(
    const float* __restrict__ H, float* __restrict__ stats, int N)
{
  const int tx = threadIdx.x & 63;
  const int ty = threadIdx.x >> 6;
  const int col = blockIdx.x * 64 + tx;
  float s1 = 0.f, s2 = 0.f;
  for (int r = blockIdx.y * 4 + ty; r < N; r += gridDim.y * 4) {
    float v = H[(size_t)r * HID + col];
    s1 += v; s2 += v * v;
  }
  __shared__ float red[2][4][64];
  red[0][ty][tx] = s1;
  red[1][ty][tx] = s2;
  __syncthreads();
  if (ty == 0) {
    s1 = red[0][0][tx] + red[0][1][tx] + red[0][2][tx] + red[0][3][tx];
    s2 = red[1][0][tx] + red[1][1][tx] + red[1][2][tx] + red[1][3][tx];
    atomicAdd(&stats[col], s1);
    atomicAdd(&stats[HID + col], s2);
  }
}

// ---------------- BN apply + ReLU -> bf16 ----------------
__global__ __launch_bounds__(256) void bn_apply_k(
    const float* __restrict__ H, const float* __restrict__ stats,
    const float* __restrict__ gamma, const float* __restrict__ beta,
    unsigned short* __restrict__ out, int N)
{
  size_t gid = (size_t)blockIdx.x * 256 + threadIdx.x;
  size_t idx = gid * 4;
  if (idx >= (size_t)N * HID) return;
  int col = (int)(idx & (HID - 1));
  const float4 v = *(const float4*)&H[idx];
  float r[4] = {v.x, v.y, v.z, v.w};
  ushort4 o;
  unsigned short* op = &o.x;
  #pragma unroll
  for (int i = 0; i < 4; i++) {
    int c = col + i;
    float mean = stats[c] * (1.0f / N);
    float var  = stats[HID + c] * (1.0f / N) - mean * mean;
    float scale = gamma[c] / sqrtf(var + BN_EPS);
    float shift = beta[c] - mean * scale;
    op[i] = f2b(fmaxf(fmaf(r[i], scale, shift), 0.0f));
  }
  *(ushort4*)&out[idx] = o;
}

// ---------------- LSTM cell part 1: cy; fp32 + strided bf16 write ----------------
__global__ __launch_bounds__(256) void cell1_k(
    const float* __restrict__ gates, const float* __restrict__ cin,
    float* __restrict__ cout, unsigned short* __restrict__ cout16, int ld16,
    int rows, int hasC)
{
  size_t gid = (size_t)blockIdx.x * 256 + threadIdx.x;
  if (gid >= (size_t)rows * HID) return;
  size_t row = gid >> 9;
  int    col = (int)(gid & (HID - 1));
  const float* g = &gates[row * G4];
  float ig = sigmoidf_(g[col]);
  float gg = tanhf(g[2 * HID + col]);
  float c;
  if (hasC) {
    float fg = sigmoidf_(g[HID + col]);
    c = fg * cin[gid] + ig * gg;
  } else {
    c = ig * gg;
  }
  cout[gid] = c;
  cout16[row * ld16 + col] = f2b(c);
}

// ---------------- LSTM cell part 2: hy; optional strided bf16 write ----------------
__global__ __launch_bounds__(256) void cell2_k(
    const float* __restrict__ gates, const float* __restrict__ cy,
    float* __restrict__ hy, unsigned short* __restrict__ hy16, int ld16, int rows)
{
  size_t gid = (size_t)blockIdx.x * 256 + threadIdx.x;
  if (gid >= (size_t)rows * HID) return;
  size_t row = gid >> 9;
  int    col = (int)(gid & (HID - 1));
  float og = sigmoidf_(gates[row * G4 + 3 * HID + col]);
  float h = og * tanhf(cy[gid]);
  hy[gid] = h;
  if (hy16) hy16[row * ld16 + col] = f2b(h);
}

// ---------------- output projection ----------------
__global__ __launch_bounds__(256) void out_k(
    const float* __restrict__ Hh, const float* __restrict__ W,
    const float* __restrict__ b, float* __restrict__ out, int rows)
{
  int wave = (int)(((size_t)blockIdx.x * 256 + threadIdx.x) >> 6);
  int lane = threadIdx.x & 63;
  if (wave >= rows) return;
  const float* hr = &Hh[(size_t)wave * HID];
  float acc[12] = {};
  for (int k = lane; k < HID; k += 64) {
    float hv = hr[k];
    const float* wr = &W[k * 12];
    #pragma unroll
    for (int p = 0; p < 12; p++) acc[p] = fmaf(hv, wr[p], acc[p]);
  }
  #pragma unroll
  for (int p = 0; p < 12; p++) {
    float v = acc[p];
    #pragma unroll
    for (int off = 32; off > 0; off >>= 1) v += __shfl_down(v, off);
    if (lane == 0) out[(size_t)wave * 12 + p] = v + b[p];
  }
}

extern "C" void kernel_launch(void* const* d_in, const int* in_sizes, int n_in,
                              void* d_out, int out_size, void* d_ws, size_t ws_size,
                              hipStream_t stream) {
  const float* x     = (const float*)d_in[0];
  const int*   ei    = (const int*)d_in[1];
  const float* ew    = (const float*)d_in[2];
  const float* gcn0W = (const float*)d_in[3];
  const float* gcnW  = (const float*)d_in[5];
  const float* gamma = (const float*)d_in[7];
  const float* beta  = (const float*)d_in[8];
  const float* wih   = (const float*)d_in[9];
  const float* whh   = (const float*)d_in[10];
  const float* wch   = (const float*)d_in[11];
  const float* lstmb = (const float*)d_in[12];
  const float* outW  = (const float*)d_in[13];
  const float* outb  = (const float*)d_in[14];
  float* out = (float*)d_out;

  const int* src = ei;
  const int* dst = ei + N_EDGES;

  const int CH = (ws_size >= (size_t)215000000) ? 10000 : 5000;
  const int NCHUNK = N_NODES / CH;

  // -------- workspace layout --------
  const size_t NH = (size_t)N_NODES * HID;
  float* ws = (float*)d_ws;
  float* gates = ws;                                 // CH*2048 fp32
  float* bufH  = gates + (size_t)CH * G4;            // NH fp32
  unsigned short* hbA16 = (unsigned short*)(bufH + NH);
  unsigned short* hbB16 = hbA16 + NH;
  unsigned short* x16   = hbB16 + NH;
  unsigned short* g0t   = x16 + (size_t)N_NODES * IN_CH;
  unsigned short* g1t   = g0t   + 512 * 64;
  unsigned short* g2t   = g1t   + 512 * 512;
  unsigned short* wih0t = g2t   + 512 * 512;             // [2048,512]
  unsigned short* wcat3 = wih0t + (size_t)2048 * 512;    // [2048,1536] fused L1 B
  unsigned short* wch0ot= wcat3 + (size_t)2048 * 1536;   // [512,512]
  unsigned short* wch1ot= wch0ot + 512 * 512;            // [512,512]
  unsigned short* wend  = wch1ot + 512 * 512;
  unsigned short *a16, *tail16;                          // concat [CH,1536]
  if (CH == 5000) {
    a16  = hbB16;                       // 5000*1536 = 7.68M <= NH
    tail16 = wend;
  } else {
    a16  = wend;
    tail16 = a16 + (size_t)CH * 1536;
  }
  float* stats = (float*)tail16;
  int*   csr   = (int*)(stats + 1024);
  int*   counts  = csr;
  int*   offsets = csr + 20032;
  int*   cpos    = csr + 40064;
  int*   s_s     = csr + 60096;
  float* w_s     = (float*)(csr + 380096);

  float* cbuf = bufH;
  float* hbuf = bufH + (size_t)CH * HID;

  const dim3 blk(256);
  auto gemm128 = [&](const unsigned short* A, const unsigned short* Bt, float* C,
                     unsigned short* C16, const float* bias,
                     int M, int K, int lda, int NC, int ldc, int acc) {
    int nrowb = (M + 127) / 128;
    int ncolb = NC / 128;
    int nblocks = 8 * ((nrowb + 7) / 8) * ncolb;
    hipLaunchKernelGGL((gemm_bf16_k<128>), dim3(nblocks), blk, 0, stream,
                       A, Bt, C, C16, bias, M, K, lda, NC, ldc, acc, nrowb, ncolb);
  };
  auto gemm64 = [&](const unsigned short* A, const unsigned short* Bt, float* C,
                    unsigned short* C16, const float* bias,
                    int M, int K, int lda, int NC, int ldc, int acc) {
    int nrowb = (M + 127) / 128;
    int ncolb = NC / 64;
    int nblocks = 8 * ((nrowb + 7) / 8) * ncolb;
    hipLaunchKernelGGL((gemm_bf16_k<64>), dim3(nblocks), blk, 0, stream,
                       A, Bt, C, C16, bias, M, K, lda, NC, ldc, acc, nrowb, ncolb);
  };
  auto tcvt = [&](const float* W, unsigned short* Wt, int K, int NC, int ldw, int ldo) {
    dim3 grid((NC + 31) / 32, (K + 31) / 32);
    hipLaunchKernelGGL(tcvt_k, grid, dim3(32, 8), 0, stream, W, Wt, K, NC, ldw, ldo);
  };
  auto zero = [&](float* p, size_t n) {
    hipLaunchKernelGGL(zero_k, dim3((unsigned)((n / 4 + 255) / 256)), blk, 0, stream, p, n);
  };

  // -------- weight prep --------
  const float* wih1 = wih + (size_t)HID * G4;
  const float* whh1 = whh + (size_t)HID * G4;
  const float* wch1 = wch + (size_t)HID * 3 * HID;
  tcvt(gcn0W, g0t, IN_CH, HID, HID, IN_CH);
  tcvt(gcnW,                     g1t, HID, HID, HID, HID);
  tcvt(gcnW + (size_t)HID * HID, g2t, HID, HID, HID, HID);
  tcvt(wih,  wih0t, HID, G4, G4, HID);
  // fused layer-1 B: [2048 x 1536] = [Wih1^T | Whh1^T | peephole block]
  zero((float*)wcat3, (size_t)2048 * 1536 / 2);
  tcvt(wih1, wcat3,       HID, G4, G4, 1536);
  tcvt(whh1, wcat3 + 512, HID, G4, G4, 1536);
  tcvt(wch1 + HID, wcat3 + (size_t)512  * 1536 + 1024, HID, HID, 3 * HID, 1536); // f
  tcvt(wch1,       wcat3 + (size_t)1024 * 1536 + 1024, HID, HID, 3 * HID, 1536); // g
  tcvt(wch + 2 * HID,  wch0ot, HID, HID, 3 * HID, HID);   // Wch0 o-peephole
  tcvt(wch1 + 2 * HID, wch1ot, HID, HID, 3 * HID, HID);   // Wch1 o-peephole
  hipLaunchKernelGGL(cvt_k, dim3((N_NODES * IN_CH / 4 + 255) / 256), blk, 0, stream,
                     x, x16, (size_t)N_NODES * IN_CH);

  // -------- CSR build --------
  const int e_blocks = (N_EDGES + 255) / 256;
  zero((float*)counts, N_NODES);
  hipLaunchKernelGGL(hist_k, dim3(e_blocks), blk, 0, stream, dst, counts);
  hipLaunchKernelGGL(scan_k, dim3(1), dim3(1024), 0, stream, counts, offsets, cpos, N_NODES);
  hipLaunchKernelGGL(fill_k, dim3(e_blocks), blk, 0, stream, src, dst, ew, cpos, s_s, w_s);

  // -------- GCN stack (NC=512 -> BN=64 kernel, 1280 blocks) --------
  const unsigned short* gWt[3] = {g0t, g1t, g2t};
  const int             gK[3]  = {IN_CH, HID, HID};
  const unsigned short* gA[3]  = {x16, hbA16, hbB16};
  unsigned short*       gO[3]  = {hbA16, hbB16, hbA16};
  unsigned short*       gXW[3] = {hbB16, hbB16, hbA16};
  for (int l = 0; l < 3; l++) {
    gemm64(gA[l], gWt[l], nullptr, gXW[l], nullptr, N_NODES, gK[l], gK[l], HID, HID, 0);
    hipLaunchKernelGGL(gather_k, dim3(N_NODES), dim3(128), 0, stream,
                       gXW[l], offsets, s_s, w_s, bufH);
    zero(stats, 2 * HID);
    hipLaunchKernelGGL(bn_stats_k, dim3(8, 64), blk, 0, stream, bufH, stats, N_NODES);
    hipLaunchKernelGGL(bn_apply_k, dim3((unsigned)(NH / 4 / 256)), blk, 0, stream,
                       bufH, stats, gamma + l * HID, beta + l * HID, gO[l], N_NODES);
  }
  unsigned short* hfin16 = hbA16;

  // -------- LSTM + output, chunked --------
  for (int ci = 0; ci < NCHUNK; ci++) {
    const int r0 = ci * CH;
    const unsigned short* h_c = hfin16 + (size_t)r0 * HID;
    const int cell_blocks = (int)(((size_t)CH * HID + 255) / 256);
    const int cpy_blocks  = (int)(((size_t)CH * HID / 4 + 255) / 256);

    // a16 row = [ h(0:512) | hy0(512:1024) | c(1024:1536) ]
    hipLaunchKernelGGL(cpy16_k, dim3(cpy_blocks), blk, 0, stream, h_c, a16, CH, 1536);

    // layer 0 (h=c=0): gates = h@Wih0 + b0
    gemm128(h_c, wih0t, gates, nullptr, lstmb, CH, HID, HID, G4, G4, 0);
    hipLaunchKernelGGL(cell1_k, dim3(cell_blocks), blk, 0, stream,
                       gates, (const float*)nullptr, cbuf, a16 + 1024, 1536, CH, 0);
    // o peephole L0: gates[:,3H:] += c0 @ Wch0_o
    gemm64(a16 + 1024, wch0ot, gates + 3 * HID, nullptr, nullptr,
           CH, HID, 1536, HID, G4, 1);
    hipLaunchKernelGGL(cell2_k, dim3(cell_blocks), blk, 0, stream,
                       gates, cbuf, hbuf, a16 + 512, 1536, CH);

    // layer 1 fused: gates = [h|hy0|c0] @ [Wih1;Whh1;0|f|g|0] + b1  (K=1536)
    gemm128(a16, wcat3, gates, nullptr, lstmb + G4, CH, 1536, 1536, G4, G4, 0);
    hipLaunchKernelGGL(cell1_k, dim3(cell_blocks), blk, 0, stream,
                       gates, cbuf, cbuf, a16 + 1024, 1536, CH, 1);   // c1 overwrites c0
    // o peephole L1: gates[:,3H:] += c1 @ Wch1_o
    gemm64(a16 + 1024, wch1ot, gates + 3 * HID, nullptr, nullptr,
           CH, HID, 1536, HID, G4, 1);
    hipLaunchKernelGGL(cell2_k, dim3(cell_blocks), blk, 0, stream,
                       gates, cbuf, hbuf, (unsigned short*)nullptr, 0, CH);

    hipLaunchKernelGGL(out_k, dim3((CH * 64 + 255) / 256), blk, 0, stream,
                       hbuf, outW, outb, out + (size_t)r0 * 12, CH);
  }
}